// Round 12
// baseline (223.514 us; speedup 1.0000x reference)
//
#include <hip/hip_runtime.h>
#include <stdint.h>

#define AS1 __attribute__((address_space(1)))
#define AS3 __attribute__((address_space(3)))

typedef __bf16 bf16x8 __attribute__((ext_vector_type(8)));
typedef float f32x4 __attribute__((ext_vector_type(4)));

constexpr int NB = 8;     // batches
constexpr int N  = 2048;  // nodes
constexpr int F  = 128;   // features (in == out)
constexpr size_t NSL = (size_t)NB * N * F;   // nump slice (floats)
constexpr size_t DSL = (size_t)NB * N;       // denp slice (floats)

__device__ __forceinline__ unsigned short bf16r(float f) {
    unsigned u = __float_as_uint(f);
    return (unsigned short)((u + 0x7FFFu + ((u >> 16) & 1u)) >> 16);
}
__device__ __forceinline__ float bf2f(unsigned short s) {
    return __uint_as_float(((unsigned)s) << 16);
}

// ---------------------------------------------------------------------------
// Wb2 element layout (MFMA-B-operand native, linear in k-chunks):
//   byte(b, n, o) = b*N*F*2 + (n>>3)*2048 + o*16 + (n&7)*2
// BK=32 chunk (j0 + c*32) = contiguous 8192 B at b*N*F*2 + (j0>>3)*2048 + c*8192.
// ---------------------------------------------------------------------------

// K1 (fused): Wh = h @ W^T;  e = Wh @ a2;  p = exp(e);
//   p16 = bf16(p);  Wb2 = bf16(bf2f(p16) * Wh)
__global__ __launch_bounds__(256) void k1_wh(const float* __restrict__ h,
                                             const float* __restrict__ W,
                                             const float* __restrict__ a,
                                             unsigned short* __restrict__ Wb2,
                                             unsigned short* __restrict__ p16) {
    __shared__ float epart[2][64];

    const int tid  = threadIdx.x;
    const int lane = tid & 63, wid = tid >> 6;
    const int quad = lane >> 4, l15 = lane & 15;
    const int wm = wid >> 1, wn = wid & 1;
    const int m0 = blockIdx.x * 64;
    const int batch = m0 >> 11;
    const int nbase = m0 & 2047;

    f32x4 acc[2][4] = {};

#pragma unroll
    for (int kk = 0; kk < 4; ++kk) {
        const int k = kk * 32 + quad * 8;
        bf16x8 afr[2], bfr[4];
#pragma unroll
        for (int rt = 0; rt < 2; ++rt) {
            const float* src = h + (size_t)(m0 + wm * 32 + rt * 16 + l15) * F + k;
            float4 x0 = *(const float4*)src;
            float4 x1 = *(const float4*)(src + 4);
            afr[rt][0] = (__bf16)x0.x; afr[rt][1] = (__bf16)x0.y;
            afr[rt][2] = (__bf16)x0.z; afr[rt][3] = (__bf16)x0.w;
            afr[rt][4] = (__bf16)x1.x; afr[rt][5] = (__bf16)x1.y;
            afr[rt][6] = (__bf16)x1.z; afr[rt][7] = (__bf16)x1.w;
        }
#pragma unroll
        for (int ct = 0; ct < 4; ++ct) {
            const int o = wn * 64 + ct * 16 + l15;
            const float* src = W + (size_t)o * F + k;
            float4 x0 = *(const float4*)src;
            float4 x1 = *(const float4*)(src + 4);
            bfr[ct][0] = (__bf16)x0.x; bfr[ct][1] = (__bf16)x0.y;
            bfr[ct][2] = (__bf16)x0.z; bfr[ct][3] = (__bf16)x0.w;
            bfr[ct][4] = (__bf16)x1.x; bfr[ct][5] = (__bf16)x1.y;
            bfr[ct][6] = (__bf16)x1.z; bfr[ct][7] = (__bf16)x1.w;
        }
#pragma unroll
        for (int rt = 0; rt < 2; ++rt)
#pragma unroll
            for (int ct = 0; ct < 4; ++ct)
                acc[rt][ct] = __builtin_amdgcn_mfma_f32_16x16x32_bf16(
                    afr[rt], bfr[ct], acc[rt][ct], 0, 0, 0);
    }

    float a2v[4];
#pragma unroll
    for (int ct = 0; ct < 4; ++ct) a2v[ct] = a[F + wn * 64 + ct * 16 + l15];

    float ep[2][4];
#pragma unroll
    for (int rt = 0; rt < 2; ++rt)
#pragma unroll
        for (int g = 0; g < 4; ++g) {
            float s = 0.f;
#pragma unroll
            for (int ct = 0; ct < 4; ++ct) s += acc[rt][ct][g] * a2v[ct];
            ep[rt][g] = s;
        }
#pragma unroll
    for (int m = 1; m < 16; m <<= 1)
#pragma unroll
        for (int rt = 0; rt < 2; ++rt)
#pragma unroll
            for (int g = 0; g < 4; ++g)
                ep[rt][g] += __shfl_xor(ep[rt][g], m);

    if (l15 == 0)
#pragma unroll
        for (int rt = 0; rt < 2; ++rt)
#pragma unroll
            for (int g = 0; g < 4; ++g)
                epart[wn][wm * 32 + rt * 16 + quad * 4 + g] = ep[rt][g];
    __syncthreads();

#pragma unroll
    for (int rt = 0; rt < 2; ++rt)
#pragma unroll
        for (int ct = 0; ct < 4; ++ct) {
            const int o  = wn * 64 + ct * 16 + l15;
            const int r0 = wm * 32 + rt * 16 + quad * 4;
            const int n0 = nbase + r0;
            ushort4 v;
#pragma unroll
            for (int g = 0; g < 4; ++g) {
                const float e  = epart[0][r0 + g] + epart[1][r0 + g];
                const float pf = bf2f(bf16r(expf(e)));
                (&v.x)[g] = bf16r(pf * acc[rt][ct][g]);
            }
            size_t off = (size_t)batch * N * F + (size_t)(n0 >> 3) * 1024 + o * 8 + (n0 & 7);
            *(ushort4*)&Wb2[off] = v;
        }

    if (tid < 64) {
        const float e = epart[0][tid] + epart[1][tid];
        p16[batch * N + nbase + tid] = bf16r(expf(e));
    }
}

// K3: PARTIAL num/denom over a j-quarter.
//   nump[jq][b][i][o] = sum_{j in q} adj[b][i][j]*Wb2[j][o]
//   denp[jq][b][i]    = sum_{j in q} adj[b][i][j]*p[j]
// Block = (batch, 64-row i-tile, 512-wide j-quarter): grid 1024 = 4 blk/CU.
// R9-proven dbuf cadence; BK=32 (1 MFMA k-step/chunk, 16 chunks). LDS:
// A dbuf 2x8 KB (64 rows x 128 B, linear), B dbuf 2x8 KB (linear Wb2 image),
// p 1 KB = 33 KB. 4 waves 2x2 (wm row-half 32, wn o-half 64).
// XCD-pin: batch = blockIdx&7.
__global__ __launch_bounds__(256) void k3_attn(const float* __restrict__ adj,
                                               const unsigned short* __restrict__ Wb2,
                                               const unsigned short* __restrict__ p16,
                                               float* __restrict__ nump,
                                               float* __restrict__ denp) {
    __shared__ __align__(16) float          At[2][64 * 32];   // 8 KB each
    __shared__ __align__(16) unsigned short Bt[2][4 * 1024];  // 8 KB each
    __shared__ __align__(16) unsigned short Pt[512];          // 1 KB

    const int tid  = threadIdx.x;
    const int lane = tid & 63, wid = tid >> 6;
    const int quad = lane >> 4, l15 = lane & 15;
    const int wm = wid >> 1, wn = wid & 1;
    const int b  = blockIdx.x & 7;
    const int r  = blockIdx.x >> 3;        // 0..127
    const int it = r >> 2, jq = r & 3;
    const int i0 = it * 64, j0 = jq * 512;

    // A staging: 8 instr/chunk (2/wave). Instr ii = wid*2+s fills LDS rows
    // ii*8..+7 (128 B rows of 32 floats). Lane: row ii*8+(lane>>3), 16B slot
    // lane&7 -> global floats (lane&7)*4 (linear, no swizzle).
    const float* aSrcs[2];
#pragma unroll
    for (int s = 0; s < 2; ++s) {
        const int ri = (wid * 2 + s) * 8 + (lane >> 3);
        aSrcs[s] = adj + (size_t)b * N * N + (size_t)(i0 + ri) * N + j0
                 + (lane & 7) * 4;
    }
    // B staging: linear 8 KB/chunk, 2 instr/wave.
    const char* bSrc = (const char*)Wb2 + (size_t)b * N * F * 2
                     + (size_t)jq * 131072 + (size_t)wid * 2048 + lane * 16;
    // p staging: 1 KB once (wave 0).
    const char* pSrc = (const char*)p16 + ((size_t)b * N + j0) * 2 + lane * 16;

    auto stage = [&](int buf, int c) {
#pragma unroll
        for (int s = 0; s < 2; ++s)
            __builtin_amdgcn_global_load_lds((const AS1 void*)(aSrcs[s] + c * 32),
                (AS3 void*)((char*)&At[buf][0] + (wid * 2 + s) * 1024), 16, 0, 0);
#pragma unroll
        for (int s = 0; s < 2; ++s)
            __builtin_amdgcn_global_load_lds(
                (const AS1 void*)(bSrc + (size_t)c * 8192 + s * 1024),
                (AS3 void*)((char*)&Bt[buf][0] + wid * 2048 + s * 1024), 16, 0, 0);
    };

    f32x4 acc[2][4] = {};
    f32x4 dacc[2] = {};

    if (wid == 0)
        __builtin_amdgcn_global_load_lds((const AS1 void*)pSrc,
            (AS3 void*)((char*)&Pt[0]), 16, 0, 0);
    stage(0, 0);

    for (int c = 0; c < 16; ++c) {
        const int cur = c & 1;
        __syncthreads();              // drains stage(c) (+p first time)
        if (c + 1 < 16) stage(cur ^ 1, c + 1);

        const char* aB = (const char*)&At[cur][0];
        bf16x8 pv = *(const bf16x8*)((const char*)&Pt[0] + c * 64 + quad * 16);

        bf16x8 af[2];
#pragma unroll
        for (int rt = 0; rt < 2; ++rt) {
            const int row = wm * 32 + rt * 16 + l15;
            f32x4 x0 = *(const f32x4*)(aB + row * 128 + quad * 32);
            f32x4 x1 = *(const f32x4*)(aB + row * 128 + quad * 32 + 16);
            af[rt][0] = (__bf16)x0[0]; af[rt][1] = (__bf16)x0[1];
            af[rt][2] = (__bf16)x0[2]; af[rt][3] = (__bf16)x0[3];
            af[rt][4] = (__bf16)x1[0]; af[rt][5] = (__bf16)x1[1];
            af[rt][6] = (__bf16)x1[2]; af[rt][7] = (__bf16)x1[3];
        }
#pragma unroll
        for (int ct = 0; ct < 4; ++ct) {
            const char* bb = (const char*)&Bt[cur][0]
                           + quad * 2048 + wn * 1024 + ct * 256 + l15 * 16;
            bf16x8 bf = *(const bf16x8*)bb;
#pragma unroll
            for (int rt = 0; rt < 2; ++rt)
                acc[rt][ct] = __builtin_amdgcn_mfma_f32_16x16x32_bf16(
                    af[rt], bf, acc[rt][ct], 0, 0, 0);
        }
#pragma unroll
        for (int rt = 0; rt < 2; ++rt)
            dacc[rt] = __builtin_amdgcn_mfma_f32_16x16x32_bf16(
                af[rt], pv, dacc[rt], 0, 0, 0);
    }

    // Partial writes (no division here).
    float* np = nump + (size_t)jq * NSL + (size_t)b * N * F;
#pragma unroll
    for (int rt = 0; rt < 2; ++rt)
#pragma unroll
        for (int ct = 0; ct < 4; ++ct) {
            const int o = wn * 64 + ct * 16 + l15;
#pragma unroll
            for (int g = 0; g < 4; ++g) {
                const int i = i0 + wm * 32 + rt * 16 + quad * 4 + g;
                np[(size_t)i * F + o] = acc[rt][ct][g];
            }
        }
    float* dp = denp + (size_t)jq * DSL + (size_t)b * N;
#pragma unroll
    for (int rt = 0; rt < 2; ++rt)
#pragma unroll
        for (int g = 0; g < 4; ++g)
            if (l15 == quad * 4 + g)
                dp[i0 + wm * 32 + rt * 16 + quad * 4 + g] = dacc[rt][g];
}

// K4: out[b][i][o] = (sum_q nump[q][b][i][o]) / (sum_q denp[q][b][i])
// 2048 blocks (XCD-aligned with k3: b = blk&7), 8 rows/block, float4/thread.
__global__ __launch_bounds__(256) void k4_reduce(const float* __restrict__ nump,
                                                 const float* __restrict__ denp,
                                                 float* __restrict__ out) {
    const int b  = blockIdx.x & 7;
    const int r0 = (blockIdx.x >> 3) * 8;
    const int row = r0 + (threadIdx.x >> 5);
    const int o4  = (threadIdx.x & 31) * 4;
    const size_t base = ((size_t)b * N + row) * F + o4;

    f32x4 s = {};
    float d = 0.f;
#pragma unroll
    for (int q = 0; q < 4; ++q) {
        s += *(const f32x4*)&nump[q * NSL + base];
        d += denp[q * DSL + (size_t)b * N + row];
    }
    const float inv = 1.0f / d;
    f32x4 o = { s[0] * inv, s[1] * inv, s[2] * inv, s[3] * inv };
    *(f32x4*)&out[base] = o;
}

// ---------------------------------------------------------------------------
extern "C" void kernel_launch(void* const* d_in, const int* in_sizes, int n_in,
                              void* d_out, int out_size, void* d_ws, size_t ws_size,
                              hipStream_t stream) {
    const float* h   = (const float*)d_in[0];
    const float* adj = (const float*)d_in[1];
    const float* W   = (const float*)d_in[2];
    const float* a   = (const float*)d_in[3];
    float* out = (float*)d_out;

    unsigned short* Wb2 = (unsigned short*)d_ws;                          // 4 MB
    unsigned short* p16 = (unsigned short*)((char*)d_ws + (4u << 20));    // 32 KB
    float* nump = (float*)((char*)d_ws + (8u << 20));                     // 32 MB
    float* denp = (float*)((char*)d_ws + (40u << 20));                    // 256 KB

    k1_wh<<<NB * N / 64, 256, 0, stream>>>(h, W, a, Wb2, p16);
    k3_attn<<<NB * 32 * 4, 256, 0, stream>>>(adj, Wb2, p16, nump, denp);
    k4_reduce<<<NB * N / 8, 256, 0, stream>>>(nump, denp, out);
}

// Round 13
// 217.469 us; speedup vs baseline: 1.0278x; 1.0278x over previous
//
#include <hip/hip_runtime.h>
#include <stdint.h>

#define AS1 __attribute__((address_space(1)))
#define AS3 __attribute__((address_space(3)))

typedef __bf16 bf16x8 __attribute__((ext_vector_type(8)));
typedef float f32x4 __attribute__((ext_vector_type(4)));

constexpr int NB = 8;     // batches
constexpr int N  = 2048;  // nodes
constexpr int F  = 128;   // features (in == out)
constexpr size_t NSL = (size_t)NB * N * F;   // nump slice (bf16 elements)
constexpr size_t DSL = (size_t)NB * N;       // denp slice (floats)

__device__ __forceinline__ unsigned short bf16r(float f) {
    unsigned u = __float_as_uint(f);
    return (unsigned short)((u + 0x7FFFu + ((u >> 16) & 1u)) >> 16);
}
__device__ __forceinline__ float bf2f(unsigned short s) {
    return __uint_as_float(((unsigned)s) << 16);
}

// ---------------------------------------------------------------------------
// Wb2 element layout (MFMA-B-operand native, linear in k-chunks):
//   byte(b, n, o) = b*N*F*2 + (n>>3)*2048 + o*16 + (n&7)*2
// BK=32 chunk (j0 + c*32) = contiguous 8192 B at b*N*F*2 + (j0>>3)*2048 + c*8192.
// ---------------------------------------------------------------------------

// K1 (fused): Wh = h @ W^T;  e = Wh @ a2;  p = exp(e);
//   p16 = bf16(p);  Wb2 = bf16(bf2f(p16) * Wh)
__global__ __launch_bounds__(256) void k1_wh(const float* __restrict__ h,
                                             const float* __restrict__ W,
                                             const float* __restrict__ a,
                                             unsigned short* __restrict__ Wb2,
                                             unsigned short* __restrict__ p16) {
    __shared__ float epart[2][64];

    const int tid  = threadIdx.x;
    const int lane = tid & 63, wid = tid >> 6;
    const int quad = lane >> 4, l15 = lane & 15;
    const int wm = wid >> 1, wn = wid & 1;
    const int m0 = blockIdx.x * 64;
    const int batch = m0 >> 11;
    const int nbase = m0 & 2047;

    f32x4 acc[2][4] = {};

#pragma unroll
    for (int kk = 0; kk < 4; ++kk) {
        const int k = kk * 32 + quad * 8;
        bf16x8 afr[2], bfr[4];
#pragma unroll
        for (int rt = 0; rt < 2; ++rt) {
            const float* src = h + (size_t)(m0 + wm * 32 + rt * 16 + l15) * F + k;
            float4 x0 = *(const float4*)src;
            float4 x1 = *(const float4*)(src + 4);
            afr[rt][0] = (__bf16)x0.x; afr[rt][1] = (__bf16)x0.y;
            afr[rt][2] = (__bf16)x0.z; afr[rt][3] = (__bf16)x0.w;
            afr[rt][4] = (__bf16)x1.x; afr[rt][5] = (__bf16)x1.y;
            afr[rt][6] = (__bf16)x1.z; afr[rt][7] = (__bf16)x1.w;
        }
#pragma unroll
        for (int ct = 0; ct < 4; ++ct) {
            const int o = wn * 64 + ct * 16 + l15;
            const float* src = W + (size_t)o * F + k;
            float4 x0 = *(const float4*)src;
            float4 x1 = *(const float4*)(src + 4);
            bfr[ct][0] = (__bf16)x0.x; bfr[ct][1] = (__bf16)x0.y;
            bfr[ct][2] = (__bf16)x0.z; bfr[ct][3] = (__bf16)x0.w;
            bfr[ct][4] = (__bf16)x1.x; bfr[ct][5] = (__bf16)x1.y;
            bfr[ct][6] = (__bf16)x1.z; bfr[ct][7] = (__bf16)x1.w;
        }
#pragma unroll
        for (int rt = 0; rt < 2; ++rt)
#pragma unroll
            for (int ct = 0; ct < 4; ++ct)
                acc[rt][ct] = __builtin_amdgcn_mfma_f32_16x16x32_bf16(
                    afr[rt], bfr[ct], acc[rt][ct], 0, 0, 0);
    }

    float a2v[4];
#pragma unroll
    for (int ct = 0; ct < 4; ++ct) a2v[ct] = a[F + wn * 64 + ct * 16 + l15];

    float ep[2][4];
#pragma unroll
    for (int rt = 0; rt < 2; ++rt)
#pragma unroll
        for (int g = 0; g < 4; ++g) {
            float s = 0.f;
#pragma unroll
            for (int ct = 0; ct < 4; ++ct) s += acc[rt][ct][g] * a2v[ct];
            ep[rt][g] = s;
        }
#pragma unroll
    for (int m = 1; m < 16; m <<= 1)
#pragma unroll
        for (int rt = 0; rt < 2; ++rt)
#pragma unroll
            for (int g = 0; g < 4; ++g)
                ep[rt][g] += __shfl_xor(ep[rt][g], m);

    if (l15 == 0)
#pragma unroll
        for (int rt = 0; rt < 2; ++rt)
#pragma unroll
            for (int g = 0; g < 4; ++g)
                epart[wn][wm * 32 + rt * 16 + quad * 4 + g] = ep[rt][g];
    __syncthreads();

#pragma unroll
    for (int rt = 0; rt < 2; ++rt)
#pragma unroll
        for (int ct = 0; ct < 4; ++ct) {
            const int o  = wn * 64 + ct * 16 + l15;
            const int r0 = wm * 32 + rt * 16 + quad * 4;
            const int n0 = nbase + r0;
            ushort4 v;
#pragma unroll
            for (int g = 0; g < 4; ++g) {
                const float e  = epart[0][r0 + g] + epart[1][r0 + g];
                const float pf = bf2f(bf16r(expf(e)));
                (&v.x)[g] = bf16r(pf * acc[rt][ct][g]);
            }
            size_t off = (size_t)batch * N * F + (size_t)(n0 >> 3) * 1024 + o * 8 + (n0 & 7);
            *(ushort4*)&Wb2[off] = v;
        }

    if (tid < 64) {
        const float e = epart[0][tid] + epart[1][tid];
        p16[batch * N + nbase + tid] = bf16r(expf(e));
    }
}

// K3: PARTIAL num/denom over a j-quarter.
//   nump[jq][b][i][o] = bf16( sum_{j in q} adj[b][i][j]*Wb2[j][o] )
//   denp[jq][b][i]    =       sum_{j in q} adj[b][i][j]*p[j]
// Block = (batch, 64-row i-tile, 512-wide j-quarter): grid 1024 = 4 blk/CU.
// R9-proven dbuf cadence; BK=32, 16 chunks. LDS: A dbuf 2x8 KB (64 rows x
// 128 B, XOR-swizzled: slot s of row r holds global chunk s^(r&7)), B dbuf
// 2x8 KB (linear Wb2 image), p 1 KB = 33 KB -> 4 blocks/CU.
// 4 waves 2x2 (wm row-half 32, wn o-half 64). XCD-pin: batch = blockIdx&7.
__global__ __launch_bounds__(256) void k3_attn(const float* __restrict__ adj,
                                               const unsigned short* __restrict__ Wb2,
                                               const unsigned short* __restrict__ p16,
                                               unsigned short* __restrict__ nump,
                                               float* __restrict__ denp) {
    __shared__ __align__(16) float          At[2][64 * 32];   // 8 KB each
    __shared__ __align__(16) unsigned short Bt[2][4 * 1024];  // 8 KB each
    __shared__ __align__(16) unsigned short Pt[512];          // 1 KB

    const int tid  = threadIdx.x;
    const int lane = tid & 63, wid = tid >> 6;
    const int quad = lane >> 4, l15 = lane & 15;
    const int wm = wid >> 1, wn = wid & 1;
    const int b  = blockIdx.x & 7;
    const int r  = blockIdx.x >> 3;        // 0..127
    const int it = r >> 2, jq = r & 3;
    const int i0 = it * 64, j0 = jq * 512;

    // A staging: 8 instr/chunk (2/wave). Instr ii = wid*2+s fills LDS rows
    // ii*8..+7 (128 B rows of 32 floats). Lane: row ri = ii*8+(lane>>3);
    // 16B slot lane&7 holds global chunk (lane&7)^(ri&7)  [XOR swizzle ->
    // readback banks spread, 2-way residual = free].
    const float* aSrcs[2];
#pragma unroll
    for (int s = 0; s < 2; ++s) {
        const int ri = (wid * 2 + s) * 8 + (lane >> 3);
        aSrcs[s] = adj + (size_t)b * N * N + (size_t)(i0 + ri) * N + j0
                 + (((lane & 7) ^ (ri & 7)) << 2);
    }
    // B staging: linear 8 KB/chunk, 2 instr/wave.
    const char* bSrc = (const char*)Wb2 + (size_t)b * N * F * 2
                     + (size_t)jq * 131072 + (size_t)wid * 2048 + lane * 16;
    // p staging: 1 KB once (wave 0).
    const char* pSrc = (const char*)p16 + ((size_t)b * N + j0) * 2 + lane * 16;

    auto stage = [&](int buf, int c) {
#pragma unroll
        for (int s = 0; s < 2; ++s)
            __builtin_amdgcn_global_load_lds((const AS1 void*)(aSrcs[s] + c * 32),
                (AS3 void*)((char*)&At[buf][0] + (wid * 2 + s) * 1024), 16, 0, 0);
#pragma unroll
        for (int s = 0; s < 2; ++s)
            __builtin_amdgcn_global_load_lds(
                (const AS1 void*)(bSrc + (size_t)c * 8192 + s * 1024),
                (AS3 void*)((char*)&Bt[buf][0] + wid * 2048 + s * 1024), 16, 0, 0);
    };

    f32x4 acc[2][4] = {};
    f32x4 dacc[2] = {};

    if (wid == 0)
        __builtin_amdgcn_global_load_lds((const AS1 void*)pSrc,
            (AS3 void*)((char*)&Pt[0]), 16, 0, 0);
    stage(0, 0);

    for (int c = 0; c < 16; ++c) {
        const int cur = c & 1;
        __syncthreads();              // drains stage(c) (+p first time)
        if (c + 1 < 16) stage(cur ^ 1, c + 1);

        const char* aB = (const char*)&At[cur][0];
        bf16x8 pv = *(const bf16x8*)((const char*)&Pt[0] + c * 64 + quad * 16);

        bf16x8 af[2];
#pragma unroll
        for (int rt = 0; rt < 2; ++rt) {
            const int row = wm * 32 + rt * 16 + l15;
            const int s0 = (quad * 2)     ^ (row & 7);
            const int s1 = (quad * 2 + 1) ^ (row & 7);
            f32x4 x0 = *(const f32x4*)(aB + row * 128 + (s0 << 4));
            f32x4 x1 = *(const f32x4*)(aB + row * 128 + (s1 << 4));
            af[rt][0] = (__bf16)x0[0]; af[rt][1] = (__bf16)x0[1];
            af[rt][2] = (__bf16)x0[2]; af[rt][3] = (__bf16)x0[3];
            af[rt][4] = (__bf16)x1[0]; af[rt][5] = (__bf16)x1[1];
            af[rt][6] = (__bf16)x1[2]; af[rt][7] = (__bf16)x1[3];
        }
#pragma unroll
        for (int ct = 0; ct < 4; ++ct) {
            const char* bb = (const char*)&Bt[cur][0]
                           + quad * 2048 + wn * 1024 + ct * 256 + l15 * 16;
            bf16x8 bf = *(const bf16x8*)bb;
#pragma unroll
            for (int rt = 0; rt < 2; ++rt)
                acc[rt][ct] = __builtin_amdgcn_mfma_f32_16x16x32_bf16(
                    af[rt], bf, acc[rt][ct], 0, 0, 0);
        }
#pragma unroll
        for (int rt = 0; rt < 2; ++rt)
            dacc[rt] = __builtin_amdgcn_mfma_f32_16x16x32_bf16(
                af[rt], pv, dacc[rt], 0, 0, 0);
    }

    // Partial writes (bf16 numerators; no division here).
    unsigned short* np = nump + (size_t)jq * NSL + (size_t)b * N * F;
#pragma unroll
    for (int rt = 0; rt < 2; ++rt)
#pragma unroll
        for (int ct = 0; ct < 4; ++ct) {
            const int o = wn * 64 + ct * 16 + l15;
#pragma unroll
            for (int g = 0; g < 4; ++g) {
                const int i = i0 + wm * 32 + rt * 16 + quad * 4 + g;
                np[(size_t)i * F + o] = bf16r(acc[rt][ct][g]);
            }
        }
    float* dp = denp + (size_t)jq * DSL + (size_t)b * N;
#pragma unroll
    for (int rt = 0; rt < 2; ++rt)
#pragma unroll
        for (int g = 0; g < 4; ++g)
            if (l15 == quad * 4 + g)
                dp[i0 + wm * 32 + rt * 16 + quad * 4 + g] = dacc[rt][g];
}

// K4: out[b][i][o] = (sum_q nump[q][b][i][o]) / (sum_q denp[q][b][i])
// 2048 blocks (XCD-aligned with k3: b = blk&7), 8 rows/block, 4 o's/thread.
__global__ __launch_bounds__(256) void k4_reduce(const unsigned short* __restrict__ nump,
                                                 const float* __restrict__ denp,
                                                 float* __restrict__ out) {
    const int b   = blockIdx.x & 7;
    const int row = (blockIdx.x >> 3) * 8 + (threadIdx.x >> 5);
    const int o4  = (threadIdx.x & 31) * 4;
    const size_t base = ((size_t)b * N + row) * F + o4;

    float s0 = 0.f, s1 = 0.f, s2 = 0.f, s3 = 0.f, d = 0.f;
#pragma unroll
    for (int q = 0; q < 4; ++q) {
        ushort4 v = *(const ushort4*)&nump[q * NSL + base];
        s0 += bf2f(v.x); s1 += bf2f(v.y); s2 += bf2f(v.z); s3 += bf2f(v.w);
        d  += denp[q * DSL + (size_t)b * N + row];
    }
    const float inv = 1.0f / d;
    f32x4 o = { s0 * inv, s1 * inv, s2 * inv, s3 * inv };
    *(f32x4*)&out[base] = o;
}

// ---------------------------------------------------------------------------
extern "C" void kernel_launch(void* const* d_in, const int* in_sizes, int n_in,
                              void* d_out, int out_size, void* d_ws, size_t ws_size,
                              hipStream_t stream) {
    const float* h   = (const float*)d_in[0];
    const float* adj = (const float*)d_in[1];
    const float* W   = (const float*)d_in[2];
    const float* a   = (const float*)d_in[3];
    float* out = (float*)d_out;

    unsigned short* Wb2  = (unsigned short*)d_ws;                         // 4 MB
    unsigned short* p16  = (unsigned short*)((char*)d_ws + (4u << 20));   // 32 KB
    unsigned short* nump = (unsigned short*)((char*)d_ws + (8u << 20));   // 16 MB
    float*          denp = (float*)((char*)d_ws + (24u << 20));           // 256 KB

    k1_wh<<<NB * N / 64, 256, 0, stream>>>(h, W, a, Wb2, p16);
    k3_attn<<<NB * 32 * 4, 256, 0, stream>>>(adj, Wb2, p16, nump, denp);
    k4_reduce<<<NB * N / 8, 256, 0, stream>>>(nump, denp, out);
}